// Round 4
// baseline (395.555 us; speedup 1.0000x reference)
//
#include <hip/hip_runtime.h>

#define LQ        22000
#define LEN_IN    22000
#define NB        2

typedef _Float16 half8 __attribute__((ext_vector_type(8)));
typedef _Float16 half4 __attribute__((ext_vector_type(4)));
typedef _Float16 half2 __attribute__((ext_vector_type(2)));
typedef float    floatx4 __attribute__((ext_vector_type(4)));

// ---------------------------------------------------------------------------
// One-shot prep: weight transposes (fp32 -> f16, (K,N)->(N,K)) + bias concat.
// ---------------------------------------------------------------------------
__global__ __launch_bounds__(256) void prep_kernel(
    const float* __restrict__ Wv, const float* __restrict__ Woff,
    const float* __restrict__ Wattn, const float* __restrict__ Wo,
    const float* __restrict__ boff, const float* __restrict__ battn,
    _Float16* __restrict__ WvT, _Float16* __restrict__ WofT,
    _Float16* __restrict__ WoT, float* __restrict__ biascat)
{
    const int i = blockIdx.x * 256 + threadIdx.x;
    if (i < 131072) {                       // Wv (256,512) -> WvT (512,256)
        int k = i >> 9, n = i & 511;
        WvT[n * 256 + k] = (_Float16)Wv[i];
    } else if (i < 163840) {                // Woff (256,128) -> WofT rows 0..127
        int j = i - 131072; int k = j >> 7, n = j & 127;
        WofT[n * 256 + k] = (_Float16)Woff[j];
    } else if (i < 180224) {                // Wattn (256,64) -> WofT rows 128..191
        int j = i - 163840; int k = j >> 6, n = j & 63;
        WofT[(128 + n) * 256 + k] = (_Float16)Wattn[j];
    } else if (i < 311296) {                // Wo (512,256) -> WoT (256,512)
        int j = i - 180224; int k = j >> 8, n = j & 255;
        WoT[n * 512 + k] = (_Float16)Wo[j];
    } else if (i < 311488) {                // bias concat (192)
        int j = i - 311296;
        biascat[j] = (j < 128) ? boff[j] : battn[j - 128];
    }
}

// ---------------------------------------------------------------------------
// f16 MFMA GEMM: C(MxN) = A(MxK) @ B(KxN) + bias, B given as BT(NxK) f16.
// A is fp32 (converted during staging) or f16, per template flag.
// 128x64 tile, BK=64, 256 threads = 4 waves; wave w -> rows w*32..w*32+31.
// ---------------------------------------------------------------------------
template<bool A_F32, bool OUT_F16>
__global__ __launch_bounds__(256) void gemm_kernel(
    const void* __restrict__ Aq,
    const _Float16* __restrict__ BT,
    const float* __restrict__ bias,
    void* __restrict__ C,
    int M, int N, int K)
{
    __shared__ __align__(16) _Float16 sA[128][72];
    __shared__ __align__(16) _Float16 sB[64][72];

    const int t  = threadIdx.x;
    const int m0 = blockIdx.x * 128;
    const int n0 = blockIdx.y * 64;

    const int w    = t >> 6;
    const int lane = t & 63;
    const int wm   = w * 32;
    const int lrow = lane & 15;
    const int lk   = (lane >> 4) * 8;

    const int ar = t >> 1;            // A staging row 0..127
    const int ah = (t & 1) * 32;      // A staging k-offset (32 elements)
    const int br = t >> 2;            // B staging row 0..63
    const int bs = (t & 3) * 16;      // B staging k-offset

    floatx4 acc[2][4] = {};

    for (int k0 = 0; k0 < K; k0 += 64) {
        const int arow = m0 + ar;
        if constexpr (A_F32) {
            const float4* src = reinterpret_cast<const float4*>(
                (const float*)Aq + (size_t)arow * K + k0 + ah);
            half4* dst = reinterpret_cast<half4*>(&sA[ar][ah]);
            #pragma unroll
            for (int j = 0; j < 8; ++j) {
                float4 v = {0.f, 0.f, 0.f, 0.f};
                if (arow < M) v = src[j];
                half4 h;
                h[0] = (_Float16)v.x; h[1] = (_Float16)v.y;
                h[2] = (_Float16)v.z; h[3] = (_Float16)v.w;
                dst[j] = h;
            }
        } else {
            int4 v0 = {0,0,0,0}, v1 = v0, v2 = v0, v3 = v0;
            if (arow < M) {
                const int4* src = reinterpret_cast<const int4*>(
                    (const _Float16*)Aq + (size_t)arow * K + k0 + ah);
                v0 = src[0]; v1 = src[1]; v2 = src[2]; v3 = src[3];
            }
            int4* dst = reinterpret_cast<int4*>(&sA[ar][ah]);
            dst[0] = v0; dst[1] = v1; dst[2] = v2; dst[3] = v3;
        }
        {
            const int4* src = reinterpret_cast<const int4*>(BT + (size_t)(n0 + br) * K + k0 + bs);
            int4* dst = reinterpret_cast<int4*>(&sB[br][bs]);
            dst[0] = src[0]; dst[1] = src[1];
        }
        __syncthreads();

        #pragma unroll
        for (int kb = 0; kb < 2; ++kb) {
            const int ko = kb * 32 + lk;
            half8 a0 = *reinterpret_cast<const half8*>(&sA[wm + lrow][ko]);
            half8 a1 = *reinterpret_cast<const half8*>(&sA[wm + 16 + lrow][ko]);
            half8 b0 = *reinterpret_cast<const half8*>(&sB[lrow][ko]);
            half8 b1 = *reinterpret_cast<const half8*>(&sB[16 + lrow][ko]);
            half8 b2 = *reinterpret_cast<const half8*>(&sB[32 + lrow][ko]);
            half8 b3 = *reinterpret_cast<const half8*>(&sB[48 + lrow][ko]);
            acc[0][0] = __builtin_amdgcn_mfma_f32_16x16x32_f16(a0, b0, acc[0][0], 0, 0, 0);
            acc[0][1] = __builtin_amdgcn_mfma_f32_16x16x32_f16(a0, b1, acc[0][1], 0, 0, 0);
            acc[0][2] = __builtin_amdgcn_mfma_f32_16x16x32_f16(a0, b2, acc[0][2], 0, 0, 0);
            acc[0][3] = __builtin_amdgcn_mfma_f32_16x16x32_f16(a0, b3, acc[0][3], 0, 0, 0);
            acc[1][0] = __builtin_amdgcn_mfma_f32_16x16x32_f16(a1, b0, acc[1][0], 0, 0, 0);
            acc[1][1] = __builtin_amdgcn_mfma_f32_16x16x32_f16(a1, b1, acc[1][1], 0, 0, 0);
            acc[1][2] = __builtin_amdgcn_mfma_f32_16x16x32_f16(a1, b2, acc[1][2], 0, 0, 0);
            acc[1][3] = __builtin_amdgcn_mfma_f32_16x16x32_f16(a1, b3, acc[1][3], 0, 0, 0);
        }
        __syncthreads();
    }

    // store: C frag mapping col=lane&15, row=(lane>>4)*4+reg
    const int crow = (lane >> 4) * 4;
    const int ccol = lane & 15;
    #pragma unroll
    for (int fm = 0; fm < 2; ++fm) {
        #pragma unroll
        for (int fn = 0; fn < 4; ++fn) {
            const int col = n0 + fn * 16 + ccol;
            const float b = bias[col];
            #pragma unroll
            for (int r2 = 0; r2 < 4; ++r2) {
                const int row = m0 + wm + fm * 16 + crow + r2;
                if (row < M) {
                    const float val = acc[fm][fn][r2] + b;
                    if (OUT_F16)
                        ((_Float16*)C)[(size_t)row * N + col] = (_Float16)val;
                    else
                        ((float*)C)[(size_t)row * N + col] = val;
                }
            }
        }
    }
}

// ---------------------------------------------------------------------------
// Sampler: block = 256 threads = 4 waves = 4 queries; each wave owns a query.
// Phase 1 (lane = sample 0..63): softmax + bilinear metadata -> LDS
//   (4 corner indices + 4 packed (w,w) half2 weights per sample).
// Phase 2 (lane = (head, 8 dims)): half8 gathers + packed f16 FMA.
// ---------------------------------------------------------------------------
__global__ __launch_bounds__(256) void sampler_kernel(
    const _Float16* __restrict__ value,   // (LEN_IN, 8, 64) f16, this image
    const _Float16* __restrict__ logits,  // (LQ, 192) f16, this image
    const float*    __restrict__ refp,    // (LQ, 2, 2), this image
    _Float16* __restrict__ sampled)       // (LQ, 512) f16
{
    const int t    = threadIdx.x;
    const int wq   = t >> 6;               // wave = query slot in block
    const int lane = t & 63;
    const int q    = blockIdx.x * 4 + wq;

    __shared__ __align__(16) int4  s_idx[4][72];
    __shared__ __align__(16) uint4 s_w[4][72];

    {   // ---- phase 1: metadata (lane = sample) ----
        const int s = lane;
        const int h = s >> 3;
        const int l = (s >> 2) & 1;
        const int p = s & 3;
        const _Float16* lg = logits + (size_t)q * 192;

        float logit[8];
        float m = -1e30f;
        #pragma unroll
        for (int j = 0; j < 8; ++j) {
            logit[j] = (float)lg[128 + h * 8 + j];
            m = fmaxf(m, logit[j]);
        }
        float den = 0.f;
        #pragma unroll
        for (int j = 0; j < 8; ++j) den += __expf(logit[j] - m);
        const float aw = __expf(logit[l * 4 + p] - m) / den;

        const int Hl = l ? 50 : 100;
        const int Wl = l ? 88 : 176;
        const int st = l ? 17600 : 0;
        const float rx = refp[q * 4 + l * 2 + 0];
        const float ry = refp[q * 4 + l * 2 + 1];
        const float ox = (float)lg[h * 16 + l * 8 + p * 2 + 0];
        const float oy = (float)lg[h * 16 + l * 8 + p * 2 + 1];

        // ((r+o)/W)*W - 0.5 == r+o-0.5 (normalizer cancels)
        const float x = rx + ox - 0.5f;
        const float y = ry + oy - 0.5f;
        const float x0f = floorf(x), y0f = floorf(y);
        const float fx = x - x0f, fy = y - y0f;
        const int x0 = (int)x0f, y0 = (int)y0f;

        int4  iv;
        uint4 wv;
        #pragma unroll
        for (int c = 0; c < 4; ++c) {
            const int xi = x0 + (c & 1);
            const int yi = y0 + (c >> 1);
            const bool valid = (xi >= 0) & (xi < Wl) & (yi >= 0) & (yi < Hl);
            const float wb = ((c & 1) ? fx : 1.f - fx) * ((c >> 1) ? fy : 1.f - fy);
            const float wz = valid ? wb * aw : 0.f;
            const int xc = min(max(xi, 0), Wl - 1);
            const int yc = min(max(yi, 0), Hl - 1);
            iv[c] = st + yc * Wl + xc;
            union { half2 h; unsigned int u; } cv;
            cv.h[0] = (_Float16)wz; cv.h[1] = cv.h[0];
            wv[c] = cv.u;
        }
        const int slot = h * 9 + (l * 4 + p);
        s_idx[wq][slot] = iv;
        s_w[wq][slot]   = wv;
    }
    __syncthreads();

    // ---- phase 2: gather + packed FMA (lane = head h, dim group d8) ----
    const int h  = lane >> 3;
    const int d8 = (lane & 7) * 8;
    const _Float16* vbase = value + h * 64 + d8;

    half2 acc0 = {0.f16, 0.f16}, acc1 = acc0, acc2 = acc0, acc3 = acc0;
    #pragma unroll
    for (int s8 = 0; s8 < 8; ++s8) {
        const int4  iv = s_idx[wq][h * 9 + s8];
        const uint4 wv = s_w[wq][h * 9 + s8];
        #pragma unroll
        for (int c = 0; c < 4; ++c) {
            const half8 v = *reinterpret_cast<const half8*>(vbase + (size_t)iv[c] * 512);
            union { unsigned int u; half2 h; } cv; cv.u = wv[c];
            const half2 wh = cv.h;
            half2 p0; p0[0] = v[0]; p0[1] = v[1];
            half2 p1; p1[0] = v[2]; p1[1] = v[3];
            half2 p2; p2[0] = v[4]; p2[1] = v[5];
            half2 p3; p3[0] = v[6]; p3[1] = v[7];
            acc0 += p0 * wh;
            acc1 += p1 * wh;
            acc2 += p2 * wh;
            acc3 += p3 * wh;
        }
    }
    half8 o;
    o[0] = acc0[0]; o[1] = acc0[1];
    o[2] = acc1[0]; o[3] = acc1[1];
    o[4] = acc2[0]; o[5] = acc2[1];
    o[6] = acc3[0]; o[7] = acc3[1];
    *reinterpret_cast<half8*>(sampled + (size_t)q * 512 + h * 64 + d8) = o;
}

// ---------------------------------------------------------------------------
extern "C" void kernel_launch(void* const* d_in, const int* in_sizes, int n_in,
                              void* d_out, int out_size, void* d_ws, size_t ws_size,
                              hipStream_t stream)
{
    const float* query  = (const float*)d_in[0];
    const float* refp   = (const float*)d_in[1];
    const float* inflat = (const float*)d_in[2];
    const float* Wv     = (const float*)d_in[3];
    const float* bv     = (const float*)d_in[4];
    const float* Woff   = (const float*)d_in[5];
    const float* boff   = (const float*)d_in[6];
    const float* Wattn  = (const float*)d_in[7];
    const float* battn  = (const float*)d_in[8];
    const float* Wo     = (const float*)d_in[9];
    const float* bo     = (const float*)d_in[10];
    float* out = (float*)d_out;

    char* ws = (char*)d_ws;
    size_t off = 0;
    auto take = [&](size_t bytes) { char* p = ws + off; off = (off + bytes + 255) & ~(size_t)255; return p; };
    _Float16* WvT     = (_Float16*)take(512 * 256 * 2);
    _Float16* WofT    = (_Float16*)take(192 * 256 * 2);
    _Float16* WoT     = (_Float16*)take(256 * 512 * 2);
    float*    biascat = (float*)   take(192 * 4);
    _Float16* value   = (_Float16*)take((size_t)NB * LEN_IN * 512 * 2);  // 45.1 MB
    _Float16* logits  = (_Float16*)take((size_t)NB * LQ * 192 * 2);     // 16.9 MB
    _Float16* sampled = (_Float16*)take((size_t)LQ * 512 * 2);          // 22.5 MB (per image, reused)

    prep_kernel<<<(311488 + 255) / 256, 256, 0, stream>>>(
        Wv, Woff, Wattn, Wo, boff, battn, WvT, WofT, WoT, biascat);

    const int M2   = NB * LQ;              // 44000
    const int MG2  = (M2 + 127) / 128;     // 344
    const int MG1  = (LQ + 127) / 128;     // 172

    // value = inflat @ Wv + bv   (both images at once, fp32 A converted in-kernel)
    gemm_kernel<true, true><<<dim3(MG2, 8), 256, 0, stream>>>(
        inflat, WvT, bv, value, M2, 512, 256);
    // logits = query @ [Woff|Wattn] + biascat
    gemm_kernel<true, true><<<dim3(MG2, 3), 256, 0, stream>>>(
        query, WofT, biascat, logits, M2, 192, 256);

    for (int n = 0; n < NB; ++n) {
        sampler_kernel<<<LQ / 4, 256, 0, stream>>>(
            value  + (size_t)n * LEN_IN * 512,
            logits + (size_t)n * LQ * 192,
            refp   + (size_t)n * LQ * 4,
            sampled);
        gemm_kernel<false, false><<<dim3(MG1, 4), 256, 0, stream>>>(
            sampled, WoT, bo, out + (size_t)n * LQ * 256, LQ, 256, 512);
    }
}